// Round 8
// baseline (322.430 us; speedup 1.0000x reference)
//
#include <hip/hip_runtime.h>
#include <math.h>

#define N_TOK 8192
#define DIM   2048
#define NE    64
#define TOPK  4
#define THETA 2e-3f
#define TPB   32                      /* tokens per strip */
#define NSTRIP (N_TOK / TPB)          /* 256 */
#define NBLK2 (NSTRIP * 2)            /* 512 blocks: strip x khalf */
#define HSTR  16                      /* hist padding: 1 counter per 64B line */

typedef short bf16x8 __attribute__((ext_vector_type(8)));
typedef float f32x4  __attribute__((ext_vector_type(4)));

// ---- workspace layout (float offsets) ----
#define OFF_LOGITS 0                          /* p0 partial -> final logits */
#define OFF_P1     (OFF_LOGITS + N_TOK * NE)  /* khalf=1 partial */
#define OFF_MAXV   (OFF_P1 + N_TOK * NE)
#define OFF_DENOM  (OFF_MAXV + N_TOK)
#define OFF_HIST   (OFF_DENOM + N_TOK)        /* int, NE*HSTR = 1024 */
#define OFF_CNT    (OFF_HIST + NE * HSTR)     /* int, 320 (arrival counters) */
#define OFF_WH     (OFF_CNT + 320)            /* NE*DIM bf16, frag-packed */
#define OFF_WL     (OFF_WH + NE * DIM / 2)
#define OFF_WT     (OFF_WL + NE * DIM / 2)    /* NE*DIM fp32 transposed */
#define OFF_WTMP   (OFF_WT + NE * DIM)        /* N_TOK*TOPK */

// pack 2 fp32 -> 2 truncated bf16 (hi) and 2 truncated bf16 of residual (lo)
__device__ inline void cvt2(float a, float b, unsigned& hi, unsigned& lo) {
    const unsigned ua = __float_as_uint(a), ub = __float_as_uint(b);
    hi = __builtin_amdgcn_perm(ub, ua, 0x07060302u);   // [a_hi16, b_hi16]
    const float ra = a - __uint_as_float(ua & 0xFFFF0000u);
    const float rb = b - __uint_as_float(ub & 0xFFFF0000u);
    lo = __builtin_amdgcn_perm(__float_as_uint(rb), __float_as_uint(ra), 0x07060302u);
}

union FragU { unsigned u[4]; bf16x8 v; uint4 q; };

__device__ inline void make_frags(const float4& p, const float4& q,
                                  bf16x8& hi, bf16x8& lo) {
    FragU H, L;
    cvt2(p.x, p.y, H.u[0], L.u[0]);
    cvt2(p.z, p.w, H.u[1], L.u[1]);
    cvt2(q.x, q.y, H.u[2], L.u[2]);
    cvt2(q.z, q.w, H.u[3], L.u[3]);
    hi = H.v; lo = L.v;
}

// W -> frag-packed (wh2, wl2): element for (kc, nt, lane, j) is
// W[e = nt*16 + (lane&15)][k = kc*32 + (lane>>4)*8 + j] at elem offset
// (kc*4+nt)*512 + lane*8 + j.  kc-major => the B slice of a 128-k window
// (4 kc's) is a contiguous 16KB.  Also wt fp32 transpose [k][e] for the
// exact recompute; zero hist + arrival counters.
__global__ __launch_bounds__(256)
void k_wc(const float* __restrict__ W, unsigned short* __restrict__ wh2,
          unsigned short* __restrict__ wl2, float* __restrict__ wt,
          int* __restrict__ hist, int* __restrict__ cnt) {
    const int t = blockIdx.x * 256 + threadIdx.x;     // 0..16383
    if (t < NE * HSTR) hist[t] = 0;
    if (t < 320) cnt[t] = 0;
    const int l  = t & 63;
    const int grp = t >> 6;                           // = kc*4 + nt, 0..255
    const int nt = grp & 3;
    const int kc = grp >> 2;
    const int e  = nt * 16 + (l & 15);
    const int k0 = kc * 32 + (l >> 4) * 8;

    const float4 p = *reinterpret_cast<const float4*>(W + (size_t)e * DIM + k0);
    const float4 q = *reinterpret_cast<const float4*>(W + (size_t)e * DIM + k0 + 4);
    FragU H, L;
    cvt2(p.x, p.y, H.u[0], L.u[0]);
    cvt2(p.z, p.w, H.u[1], L.u[1]);
    cvt2(q.x, q.y, H.u[2], L.u[2]);
    cvt2(q.z, q.w, H.u[3], L.u[3]);
    const size_t off = (size_t)grp * 512 + l * 8;
    *reinterpret_cast<uint4*>(wh2 + off) = H.q;
    *reinterpret_cast<uint4*>(wl2 + off) = L.q;

    wt[(size_t)(k0 + 0) * NE + e] = p.x;
    wt[(size_t)(k0 + 1) * NE + e] = p.y;
    wt[(size_t)(k0 + 2) * NE + e] = p.z;
    wt[(size_t)(k0 + 3) * NE + e] = p.w;
    wt[(size_t)(k0 + 4) * NE + e] = q.x;
    wt[(size_t)(k0 + 5) * NE + e] = q.y;
    wt[(size_t)(k0 + 6) * NE + e] = q.z;
    wt[(size_t)(k0 + 7) * NE + e] = q.w;
}

// Split-K GEMM: block (strip, khalf) computes 32 tokens x 64 experts over
// k in [khalf*1024, +1024).  512 blocks -> 2 blocks/CU (the concurrency
// that sets delivery rate).  8 windows of K=128; per window stage 48KB
// via global_load_lds (A 16KB XOR-swizzled source / linear dest, Bh+Bl
// 32KB frag-packed linear).  8 waves = 2 token-groups x 4 expert-groups,
// each wave owns a full 16x16 tile over block-K (no intra-block k-reduce).
// Partials stored raw to p0/p1; last-arriving block of the strip sums
// (deterministic p0+p1+bias), then stats + THETA-flagged exact recompute
// + histogram + fast-path out.
__global__ __launch_bounds__(512, 4)
void k_main(const float* __restrict__ x, const unsigned short* __restrict__ wh2,
            const unsigned short* __restrict__ wl2, const float* __restrict__ bias,
            const float* __restrict__ wt, float* __restrict__ p0,
            float* __restrict__ p1, float* __restrict__ maxv,
            float* __restrict__ denomv, int* __restrict__ hist,
            int* __restrict__ cnt, float* __restrict__ out) {
    __shared__ __align__(16) char smem[49152];   // A 16K | Bh 16K | Bl 16K
    __shared__ int flagCnt, arrive;

    const int tid   = threadIdx.x;
    const int ww    = tid >> 6;          // wave 0..7
    const int l     = tid & 63;
    const int strip = blockIdx.x >> 1;
    const int khalf = blockIdx.x & 1;
    const int t0    = strip * TPB;
    const int m     = l & 15;            // token-low (A) / expert-low (B)
    const int g     = l >> 4;            // k-octet group
    const int tg    = ww >> 2;           // token group 0..1
    const int eg    = ww & 3;            // expert group 0..3

    f32x4 accA, accB;
    #pragma unroll
    for (int r = 0; r < 4; ++r) { accA[r] = 0.0f; accB[r] = 0.0f; }

    const int arow = tg * 16 + m;        // A row this lane feeds
    const int axor = arow & 15;          // A slot swizzle

    for (int win = 0; win < 8; ++win) {
        // ---- stage 48KB: wave ww copies bytes [ww*6144, +6144) ----
        #pragma unroll
        for (int j = 0; j < 6; ++j) {
            const int dbase = ww * 6144 + j * 1024;    // wave-uniform
            const int d = dbase + l * 16;
            const char* src;
            if (dbase < 16384) {
                const int r = d >> 9;                  // token row 0..31
                const int p = (d >> 4) & 31;           // physical 16B slot
                const int s = p ^ (r & 15);            // logical slot
                src = (const char*)(x + (size_t)(t0 + r) * DIM
                                    + khalf * 1024 + win * 128 + s * 4);
            } else if (dbase < 32768) {
                src = (const char*)wh2 + (size_t)(khalf * 8 + win) * 16384 + (d - 16384);
            } else {
                src = (const char*)wl2 + (size_t)(khalf * 8 + win) * 16384 + (d - 32768);
            }
            __builtin_amdgcn_global_load_lds(
                (const __attribute__((address_space(1))) void*)src,
                (__attribute__((address_space(3))) void*)(smem + dbase),
                16, 0, 0);
        }
        asm volatile("s_waitcnt vmcnt(0)" ::: "memory");
        __syncthreads();

        // ---- compute: 4 k-chunks x {2 A ds_reads, cvt, 2 B reads, 3 MFMA} --
        const char* A = smem + arow * 512;
        #pragma unroll
        for (int kc = 0; kc < 4; ++kc) {
            const int s0 = kc * 8 + g * 2;
            const float4 pf = *reinterpret_cast<const float4*>(A + ((s0 ^ axor) << 4));
            const float4 qf = *reinterpret_cast<const float4*>(A + (((s0 + 1) ^ axor) << 4));
            bf16x8 ah, al;
            make_frags(pf, qf, ah, al);
            FragU bh_, bl_;
            bh_.q = *reinterpret_cast<const uint4*>(smem + 16384 + (kc * 4 + eg) * 1024 + l * 16);
            bl_.q = *reinterpret_cast<const uint4*>(smem + 32768 + (kc * 4 + eg) * 1024 + l * 16);
            accA = __builtin_amdgcn_mfma_f32_16x16x32_bf16(ah, bh_.v, accA, 0, 0, 0);
            accB = __builtin_amdgcn_mfma_f32_16x16x32_bf16(al, bh_.v, accB, 0, 0, 0);
            accB = __builtin_amdgcn_mfma_f32_16x16x32_bf16(ah, bl_.v, accB, 0, 0, 0);
        }
        __syncthreads();
    }

    // ---- store raw partial (C/D map: col=lane&15=expert, row=g*4+r) ----
    {
        float* dst = khalf ? p1 : p0;
        #pragma unroll
        for (int r = 0; r < 4; ++r)
            dst[(size_t)(t0 + tg * 16 + g * 4 + r) * NE + eg * 16 + m] = accA[r] + accB[r];
    }
    __threadfence();
    __syncthreads();
    if (tid == 0) arrive = atomicAdd(&cnt[strip], 1);
    __syncthreads();
    if (arrive == 0) return;             // first-arriving block exits
    __threadfence();                     // acquire other half's stores

    // ================= epilogue (one block per strip) =================
    float* lbuf    = reinterpret_cast<float*>(smem);            // [32][68]
    float* part    = reinterpret_cast<float*>(smem + 8704);     // [8][68]
    int*   selS    = reinterpret_cast<int*>(smem + 10880);      // [32]
    float* wS      = reinterpret_cast<float*>(smem + 11008);    // [32]
    short* flagIdx = reinterpret_cast<short*>(smem + 11136);    // [32]

    if (tid == 0) flagCnt = 0;
    for (int e2 = tid; e2 < TPB * NE; e2 += 512) {
        const int t = e2 >> 6, e = e2 & 63;
        const size_t idx = (size_t)(t0 + t) * NE + e;
        const float s = p0[idx] + p1[idx] + bias[e];
        p0[idx] = s;                     // final logits (k_decide fallback)
        lbuf[t * 68 + e] = s;
    }
    __syncthreads();

    #pragma unroll
    for (int tt = 0; tt < 4; ++tt) {
        const int t = ww * 4 + tt;
        const float lv = lbuf[t * 68 + l];
        float v1 = lv; int i1 = l; float v2 = -INFINITY;
        #pragma unroll
        for (int off = 32; off; off >>= 1) {
            const float ov1 = __shfl_xor(v1, off);
            const int   oi1 = __shfl_xor(i1, off);
            const float ov2 = __shfl_xor(v2, off);
            if (ov1 > v1 || (ov1 == v1 && oi1 < i1)) {
                v2 = fmaxf(v1, ov2); v1 = ov1; i1 = oi1;
            } else {
                v2 = fmaxf(v2, ov1);
            }
        }
        float s = expf(lv - v1);
        #pragma unroll
        for (int off = 32; off; off >>= 1) s += __shfl_xor(s, off);
        if (l == 0) {
            const int row = t0 + t;
            maxv[row]   = v1;
            denomv[row] = s;
            selS[t]     = i1;
            wS[t]       = 1.0f / s;
            if (v1 - v2 < THETA) {
                const int ix = atomicAdd(&flagCnt, 1);
                flagIdx[ix] = (short)t;
            }
        }
    }
    __syncthreads();

    // ---- in-block exact fp32 recompute for flagged (near-tie) tokens ----
    const int nf = flagCnt;
    for (int fi = 0; fi < nf; ++fi) {
        const int tl  = flagIdx[fi];
        const int row = t0 + tl;
        const float* xr = x + (size_t)row * DIM + ww * 256;
        const float* wb = wt + (size_t)(ww * 256) * NE + l;
        float a0 = 0.0f, a1 = 0.0f;
        #pragma unroll 4
        for (int k = 0; k < 256; k += 8) {
            const float4 x0 = *reinterpret_cast<const float4*>(xr + k);
            const float4 x1 = *reinterpret_cast<const float4*>(xr + k + 4);
            a0 = fmaf(x0.x, wb[(size_t)(k + 0) * NE], a0);
            a0 = fmaf(x0.y, wb[(size_t)(k + 1) * NE], a0);
            a0 = fmaf(x0.z, wb[(size_t)(k + 2) * NE], a0);
            a0 = fmaf(x0.w, wb[(size_t)(k + 3) * NE], a0);
            a1 = fmaf(x1.x, wb[(size_t)(k + 4) * NE], a1);
            a1 = fmaf(x1.y, wb[(size_t)(k + 5) * NE], a1);
            a1 = fmaf(x1.z, wb[(size_t)(k + 6) * NE], a1);
            a1 = fmaf(x1.w, wb[(size_t)(k + 7) * NE], a1);
        }
        part[ww * 68 + l] = a0 + a1;
        __syncthreads();
        if (ww == 0) {
            float lg = bias[l];
            #pragma unroll
            for (int s2 = 0; s2 < 8; ++s2) lg += part[s2 * 68 + l];
            p0[(size_t)row * NE + l] = lg;
            float v = lg; int idx = l;
            #pragma unroll
            for (int off = 32; off; off >>= 1) {
                const float ov = __shfl_xor(v, off);
                const int   oi = __shfl_xor(idx, off);
                if (ov > v || (ov == v && oi < idx)) { v = ov; idx = oi; }
            }
            float p = expf(lg - v);
            #pragma unroll
            for (int off = 32; off; off >>= 1) p += __shfl_xor(p, off);
            if (l == 0) {
                maxv[row]   = v;
                denomv[row] = p;
                selS[tl]    = idx;
                wS[tl]      = 1.0f / p;
            }
        }
        __syncthreads();
    }

    // ---- selection histogram: wave 0, lane = expert; padded counters ----
    if (ww == 0) {
        int cnt2 = 0;
        #pragma unroll
        for (int t = 0; t < TPB; ++t) cnt2 += (selS[t] == l) ? 1 : 0;
        if (cnt2) atomicAdd(&hist[l * HSTR], cnt2);
    }

    // ---- fast-path out write (k_decide fixes up only on capacity overflow) --
    if (tid < TPB) {
        const int row = t0 + tid;
        const float se = (float)selS[tid];
        const float wv = wS[tid];
        const float wn = wv / (4.0f * wv + 1e-8f);
        *reinterpret_cast<float4*>(out + (size_t)row * 4) = make_float4(se, se, se, se);
        *reinterpret_cast<float4*>(out + (size_t)N_TOK * TOPK + (size_t)row * 4) =
            make_float4(wn, wn, wn, wn);
    }
}

// capacity check from hist; out already holds the fast path. Single block:
// if any expert over capacity, run the exact serial fallback.
__global__ __launch_bounds__(256)
void k_decide(const int* __restrict__ hist, const float* __restrict__ logits,
              const float* __restrict__ maxv, const float* __restrict__ denomv,
              const int* __restrict__ tc, float* __restrict__ out,
              float* __restrict__ wtmp) {
    __shared__ int flagS;
    const int tid = threadIdx.x;
    const int cap = tc[0] / TOPK;
    if (tid < NE) {
        const bool bad = (TOPK * hist[tid * HSTR] > cap);
        const unsigned long long mm = __ballot(bad);
        if (tid == 0) flagS = (mm == 0ull) ? 1 : 0;
    }
    __syncthreads();
    if (flagS) return;                 // fast path already written by k_main

    if (tid < 64) {
        const int e = tid;
        int rem = cap;
        for (int k = 0; k < TOPK; ++k) {
            for (int b = 0; b < N_TOK; ++b) {
                const float lg = logits[(size_t)b * NE + e];
                float v = (rem > 0) ? lg : -INFINITY;
                int idx = e;
                #pragma unroll
                for (int off = 32; off; off >>= 1) {
                    const float ov = __shfl_xor(v, off);
                    const int   oi = __shfl_xor(idx, off);
                    if (ov > v || (ov == v && oi < idx)) { v = ov; idx = oi; }
                }
                const bool ok = (v != -INFINITY);
                if (ok && e == idx) rem -= 1;
                const float lc = __shfl(lg, idx);
                if (e == 0) {
                    out[(size_t)b * TOPK + k]  = ok ? (float)idx : -1.0f;
                    wtmp[(size_t)b * TOPK + k] = ok ? expf(lc - maxv[b]) / denomv[b] : 0.0f;
                }
            }
        }
    }
    __syncthreads();
    for (int b = tid; b < N_TOK; b += 256) {
        const float w0 = wtmp[b * 4 + 0], w1_ = wtmp[b * 4 + 1];
        const float w2 = wtmp[b * 4 + 2], w3 = wtmp[b * 4 + 3];
        const float s = ((w0 + w1_) + w2) + w3 + 1e-8f;
        out[N_TOK * TOPK + b * 4 + 0] = w0 / s;
        out[N_TOK * TOPK + b * 4 + 1] = w1_ / s;
        out[N_TOK * TOPK + b * 4 + 2] = w2 / s;
        out[N_TOK * TOPK + b * 4 + 3] = w3 / s;
    }
}

extern "C" void kernel_launch(void* const* d_in, const int* in_sizes, int n_in,
                              void* d_out, int out_size, void* d_ws, size_t ws_size,
                              hipStream_t stream) {
    const float* x    = (const float*)d_in[0];
    const float* W    = (const float*)d_in[1];
    const float* bias = (const float*)d_in[2];
    const int*   tc   = (const int*)d_in[3];

    float* ws       = (float*)d_ws;
    float* logits   = ws + OFF_LOGITS;
    float* p1       = ws + OFF_P1;
    float* maxv     = ws + OFF_MAXV;
    float* denomv   = ws + OFF_DENOM;
    int*   hist     = (int*)(ws + OFF_HIST);
    int*   cnt      = (int*)(ws + OFF_CNT);
    unsigned short* wh2 = (unsigned short*)(ws + OFF_WH);
    unsigned short* wl2 = (unsigned short*)(ws + OFF_WL);
    float* wt       = ws + OFF_WT;
    float* wtmp     = ws + OFF_WTMP;
    float* out      = (float*)d_out;

    k_wc<<<NE * DIM / 8 / 256, 256, 0, stream>>>(W, wh2, wl2, wt, hist, cnt);
    k_main<<<NBLK2, 512, 0, stream>>>(x, wh2, wl2, bias, wt, logits, p1,
                                      maxv, denomv, hist, cnt, out);
    k_decide<<<1, 256, 0, stream>>>(hist, logits, maxv, denomv, tc, out, wtmp);
}

// Round 10
// 153.104 us; speedup vs baseline: 2.1060x; 2.1060x over previous
//
#include <hip/hip_runtime.h>
#include <math.h>

#define N_TOK 8192
#define DIM   2048
#define NE    64
#define TOPK  4
#define THETA 2e-3f
#define TPB   64                      /* tokens per strip */
#define NSPL  4                       /* K splits */
#define NSTRIP (N_TOK / TPB)          /* 128 */
#define NBLK2 (NSTRIP * NSPL)         /* 512 blocks */
#define HSTR  16                      /* hist padding: 1 counter per 64B line */

typedef short bf16x8 __attribute__((ext_vector_type(8)));
typedef float f32x4  __attribute__((ext_vector_type(4)));

// ---- workspace layout (float offsets) ----
#define OFF_LOGITS 0                          /* final logits, N_TOK*NE */
#define OFF_P      (OFF_LOGITS + N_TOK * NE)  /* partials, NSPL*N_TOK*NE */
#define OFF_MAXV   (OFF_P + NSPL * N_TOK * NE)
#define OFF_DENOM  (OFF_MAXV + N_TOK)
#define OFF_HIST   (OFF_DENOM + N_TOK)        /* int, NE*HSTR = 1024 */
#define OFF_WH     (OFF_HIST + NE * HSTR)     /* NE*DIM bf16, frag-packed */
#define OFF_WL     (OFF_WH + NE * DIM / 2)
#define OFF_WT     (OFF_WL + NE * DIM / 2)    /* NE*DIM fp32 transposed */
#define OFF_WTMP   (OFF_WT + NE * DIM)        /* N_TOK*TOPK */

// pack 2 fp32 -> 2 truncated bf16 (hi) and 2 truncated bf16 of residual (lo)
__device__ inline void cvt2(float a, float b, unsigned& hi, unsigned& lo) {
    const unsigned ua = __float_as_uint(a), ub = __float_as_uint(b);
    hi = __builtin_amdgcn_perm(ub, ua, 0x07060302u);   // [a_hi16, b_hi16]
    const float ra = a - __uint_as_float(ua & 0xFFFF0000u);
    const float rb = b - __uint_as_float(ub & 0xFFFF0000u);
    lo = __builtin_amdgcn_perm(__float_as_uint(rb), __float_as_uint(ra), 0x07060302u);
}

union FragU { unsigned u[4]; bf16x8 v; uint4 q; };

__device__ inline void make_frags(const float4& p, const float4& q,
                                  bf16x8& hi, bf16x8& lo) {
    FragU H, L;
    cvt2(p.x, p.y, H.u[0], L.u[0]);
    cvt2(p.z, p.w, H.u[1], L.u[1]);
    cvt2(q.x, q.y, H.u[2], L.u[2]);
    cvt2(q.z, q.w, H.u[3], L.u[3]);
    hi = H.v; lo = L.v;
}

// W -> frag-packed (wh2, wl2): element for (kc, nt, lane, j) is
// W[e = nt*16 + (lane&15)][k = kc*32 + (lane>>4)*8 + j] at elem offset
// (kc*4+nt)*512 + lane*8 + j.  kc-major => the B slice of a 128-k window
// wk is the contiguous 16KB at wk*16384 bytes.  Also wt fp32 transpose
// [k][e] for the exact recompute; zero hist.
__global__ __launch_bounds__(256)
void k_wc(const float* __restrict__ W, unsigned short* __restrict__ wh2,
          unsigned short* __restrict__ wl2, float* __restrict__ wt,
          int* __restrict__ hist) {
    const int t = blockIdx.x * 256 + threadIdx.x;     // 0..16383
    if (t < NE * HSTR) hist[t] = 0;
    const int l  = t & 63;
    const int grp = t >> 6;                           // = kc*4 + nt, 0..255
    const int nt = grp & 3;
    const int kc = grp >> 2;
    const int e  = nt * 16 + (l & 15);
    const int k0 = kc * 32 + (l >> 4) * 8;

    const float4 p = *reinterpret_cast<const float4*>(W + (size_t)e * DIM + k0);
    const float4 q = *reinterpret_cast<const float4*>(W + (size_t)e * DIM + k0 + 4);
    FragU H, L;
    cvt2(p.x, p.y, H.u[0], L.u[0]);
    cvt2(p.z, p.w, H.u[1], L.u[1]);
    cvt2(q.x, q.y, H.u[2], L.u[2]);
    cvt2(q.z, q.w, H.u[3], L.u[3]);
    const size_t off = (size_t)grp * 512 + l * 8;
    *reinterpret_cast<uint4*>(wh2 + off) = H.q;
    *reinterpret_cast<uint4*>(wl2 + off) = L.q;

    wt[(size_t)(k0 + 0) * NE + e] = p.x;
    wt[(size_t)(k0 + 1) * NE + e] = p.y;
    wt[(size_t)(k0 + 2) * NE + e] = p.z;
    wt[(size_t)(k0 + 3) * NE + e] = p.w;
    wt[(size_t)(k0 + 4) * NE + e] = q.x;
    wt[(size_t)(k0 + 5) * NE + e] = q.y;
    wt[(size_t)(k0 + 6) * NE + e] = q.z;
    wt[(size_t)(k0 + 7) * NE + e] = q.w;
}

// Split-K GEMM: block (strip, kq) computes 64 tokens x 64 experts over
// k in [kq*512, +512).  512 blocks -> 2/CU.  4 windows of K=128, each
// staged 64KB via global_load_lds (A 32KB XOR-swizzled source / linear
// dest; Bh+Bl 32KB frag-packed linear).  8 waves = 4 token-groups x
// 2 expert-groups(32); wave owns 16x32 over block-K.  Raw partials to
// P[kq]; NO cross-block sync (kernel boundary is the fence).
__global__ __launch_bounds__(512, 4)
void k_main(const float* __restrict__ x, const unsigned short* __restrict__ wh2,
            const unsigned short* __restrict__ wl2, float* __restrict__ P) {
    __shared__ __align__(16) char smem[65536];   // A 32K | Bh 16K | Bl 16K

    const int tid   = threadIdx.x;
    const int ww    = tid >> 6;          // wave 0..7
    const int l     = tid & 63;
    const int strip = blockIdx.x >> 2;
    const int kq    = blockIdx.x & 3;
    const int t0    = strip * TPB;
    const int m     = l & 15;            // token-low (A) / expert-low (B)
    const int g     = l >> 4;            // k-octet group
    const int tg    = ww >> 1;           // token group 0..3
    const int eg    = ww & 1;            // expert group 0..1 (32 experts)

    f32x4 accA[2], accB[2];
    #pragma unroll
    for (int n = 0; n < 2; ++n)
        #pragma unroll
        for (int r = 0; r < 4; ++r) { accA[n][r] = 0.0f; accB[n][r] = 0.0f; }

    const int arow = tg * 16 + m;        // A row this lane feeds (0..63)
    const int axor = arow & 15;          // A slot swizzle

    for (int win = 0; win < 4; ++win) {
        const int wk = kq * 4 + win;     // global 128-k window index
        // ---- stage 64KB: wave ww copies bytes [ww*8192, +8192) ----
        #pragma unroll
        for (int j = 0; j < 8; ++j) {
            const int dbase = ww * 8192 + j * 1024;    // wave-uniform
            const int d = dbase + l * 16;
            const char* src;
            if (dbase < 32768) {
                const int r = d >> 9;                  // token row 0..63
                const int p = (d >> 4) & 31;           // physical 16B slot
                const int s = p ^ (r & 15);            // logical slot
                src = (const char*)(x + (size_t)(t0 + r) * DIM
                                    + wk * 128 + s * 4);
            } else if (dbase < 49152) {
                src = (const char*)wh2 + (size_t)wk * 16384 + (d - 32768);
            } else {
                src = (const char*)wl2 + (size_t)wk * 16384 + (d - 49152);
            }
            __builtin_amdgcn_global_load_lds(
                (const __attribute__((address_space(1))) void*)src,
                (__attribute__((address_space(3))) void*)(smem + dbase),
                16, 0, 0);
        }
        asm volatile("s_waitcnt vmcnt(0)" ::: "memory");
        __syncthreads();

        // ---- compute: 4 k-chunks x {A reads+cvt, 2 nt-tiles x 3 MFMA} ----
        const char* A = smem + arow * 512;
        #pragma unroll
        for (int kc = 0; kc < 4; ++kc) {
            const int s0 = kc * 8 + g * 2;
            const float4 pf = *reinterpret_cast<const float4*>(A + ((s0 ^ axor) << 4));
            const float4 qf = *reinterpret_cast<const float4*>(A + (((s0 + 1) ^ axor) << 4));
            bf16x8 ah, al;
            make_frags(pf, qf, ah, al);
            #pragma unroll
            for (int n = 0; n < 2; ++n) {
                const int nt = eg * 2 + n;
                FragU bh_, bl_;
                bh_.q = *reinterpret_cast<const uint4*>(smem + 32768 + (kc * 4 + nt) * 1024 + l * 16);
                bl_.q = *reinterpret_cast<const uint4*>(smem + 49152 + (kc * 4 + nt) * 1024 + l * 16);
                accA[n] = __builtin_amdgcn_mfma_f32_16x16x32_bf16(ah, bh_.v, accA[n], 0, 0, 0);
                accB[n] = __builtin_amdgcn_mfma_f32_16x16x32_bf16(al, bh_.v, accB[n], 0, 0, 0);
                accB[n] = __builtin_amdgcn_mfma_f32_16x16x32_bf16(ah, bl_.v, accB[n], 0, 0, 0);
            }
        }
        __syncthreads();
    }

    // ---- raw partial store (C/D map: col=lane&15=expert-low, row=g*4+r) ----
    float* dst = P + (size_t)kq * N_TOK * NE;
    #pragma unroll
    for (int n = 0; n < 2; ++n)
        #pragma unroll
        for (int r = 0; r < 4; ++r)
            dst[(size_t)(t0 + tg * 16 + g * 4 + r) * NE + eg * 32 + n * 16 + m] =
                accA[n][r] + accB[n][r];
}

// Reduce partials + bias -> logits; stats; THETA-flagged exact recompute;
// histogram; fast-path out.  256 blocks x 256 thr, 32 tokens each.
__global__ __launch_bounds__(256)
void k_reduce(const float* __restrict__ P, const float* __restrict__ bias,
              const float* __restrict__ x, const float* __restrict__ wt,
              float* __restrict__ logits, float* __restrict__ maxv,
              float* __restrict__ denomv, int* __restrict__ hist,
              float* __restrict__ out) {
    __shared__ float lbuf[32][68];
    __shared__ float part[4][68];
    __shared__ int   selS[32];
    __shared__ float wS[32];
    __shared__ short flagIdx[32];
    __shared__ int   flagCnt;

    const int tid = threadIdx.x;
    const int ww  = tid >> 6;            // wave 0..3
    const int l   = tid & 63;
    const int t0  = blockIdx.x * 32;

    if (tid == 0) flagCnt = 0;

    // sum 4 partials + bias (float4 over experts)
    for (int q = tid; q < 32 * 16; q += 256) {
        const int t = q >> 4, e4 = (q & 15) << 2;
        const size_t idx = (size_t)(t0 + t) * NE + e4;
        float4 s = *reinterpret_cast<const float4*>(P + idx);
        const float4 b1 = *reinterpret_cast<const float4*>(P + (size_t)N_TOK * NE + idx);
        const float4 b2 = *reinterpret_cast<const float4*>(P + (size_t)2 * N_TOK * NE + idx);
        const float4 b3 = *reinterpret_cast<const float4*>(P + (size_t)3 * N_TOK * NE + idx);
        const float4 bb = *reinterpret_cast<const float4*>(bias + e4);
        s.x += b1.x + b2.x + b3.x + bb.x;
        s.y += b1.y + b2.y + b3.y + bb.y;
        s.z += b1.z + b2.z + b3.z + bb.z;
        s.w += b1.w + b2.w + b3.w + bb.w;
        *reinterpret_cast<float4*>(logits + idx) = s;
        *reinterpret_cast<float4*>(&lbuf[t][e4]) = s;
    }
    __syncthreads();

    #pragma unroll
    for (int tt = 0; tt < 8; ++tt) {
        const int t = ww * 8 + tt;
        const float lv = lbuf[t][l];
        float v1 = lv; int i1 = l; float v2 = -INFINITY;
        #pragma unroll
        for (int off = 32; off; off >>= 1) {
            const float ov1 = __shfl_xor(v1, off);
            const int   oi1 = __shfl_xor(i1, off);
            const float ov2 = __shfl_xor(v2, off);
            if (ov1 > v1 || (ov1 == v1 && oi1 < i1)) {
                v2 = fmaxf(v1, ov2); v1 = ov1; i1 = oi1;
            } else {
                v2 = fmaxf(v2, ov1);
            }
        }
        float s = expf(lv - v1);
        #pragma unroll
        for (int off = 32; off; off >>= 1) s += __shfl_xor(s, off);
        if (l == 0) {
            const int row = t0 + t;
            maxv[row]   = v1;
            denomv[row] = s;
            selS[t]     = i1;
            wS[t]       = 1.0f / s;
            if (v1 - v2 < THETA) {
                const int ix = atomicAdd(&flagCnt, 1);
                flagIdx[ix] = (short)t;
            }
        }
    }
    __syncthreads();

    // ---- exact fp32 recompute for flagged (near-tie) tokens ----
    const int nf = flagCnt;
    for (int fi = 0; fi < nf; ++fi) {
        const int tl  = flagIdx[fi];
        const int row = t0 + tl;
        // 4 waves split K: wave ww covers k in [ww*512, +512); lane = expert
        const float* xr = x + (size_t)row * DIM + ww * 512;
        const float* wb = wt + (size_t)(ww * 512) * NE + l;
        float a0 = 0.0f, a1 = 0.0f;
        #pragma unroll 4
        for (int k = 0; k < 512; k += 8) {
            const float4 x0 = *reinterpret_cast<const float4*>(xr + k);
            const float4 x1 = *reinterpret_cast<const float4*>(xr + k + 4);
            a0 = fmaf(x0.x, wb[(size_t)(k + 0) * NE], a0);
            a0 = fmaf(x0.y, wb[(size_t)(k + 1) * NE], a0);
            a0 = fmaf(x0.z, wb[(size_t)(k + 2) * NE], a0);
            a0 = fmaf(x0.w, wb[(size_t)(k + 3) * NE], a0);
            a1 = fmaf(x1.x, wb[(size_t)(k + 4) * NE], a1);
            a1 = fmaf(x1.y, wb[(size_t)(k + 5) * NE], a1);
            a1 = fmaf(x1.z, wb[(size_t)(k + 6) * NE], a1);
            a1 = fmaf(x1.w, wb[(size_t)(k + 7) * NE], a1);
        }
        part[ww][l] = a0 + a1;
        __syncthreads();
        if (ww == 0) {
            float lg = bias[l];
            #pragma unroll
            for (int s2 = 0; s2 < 4; ++s2) lg += part[s2][l];
            logits[(size_t)row * NE + l] = lg;
            float v = lg; int idx = l;
            #pragma unroll
            for (int off = 32; off; off >>= 1) {
                const float ov = __shfl_xor(v, off);
                const int   oi = __shfl_xor(idx, off);
                if (ov > v || (ov == v && oi < idx)) { v = ov; idx = oi; }
            }
            float p = expf(lg - v);
            #pragma unroll
            for (int off = 32; off; off >>= 1) p += __shfl_xor(p, off);
            if (l == 0) {
                maxv[row]   = v;
                denomv[row] = p;
                selS[tl]    = idx;
                wS[tl]      = 1.0f / p;
            }
        }
        __syncthreads();
    }

    // ---- selection histogram: wave 0, lane = expert; padded counters ----
    if (ww == 0) {
        int cnt = 0;
        #pragma unroll
        for (int t = 0; t < 32; ++t) cnt += (selS[t] == l) ? 1 : 0;
        if (cnt) atomicAdd(&hist[l * HSTR], cnt);
    }

    // ---- fast-path out write (k_decide fixes up only on capacity overflow) --
    if (tid < 32) {
        const int row = t0 + tid;
        const float se = (float)selS[tid];
        const float wv = wS[tid];
        const float wn = wv / (4.0f * wv + 1e-8f);
        *reinterpret_cast<float4*>(out + (size_t)row * 4) = make_float4(se, se, se, se);
        *reinterpret_cast<float4*>(out + (size_t)N_TOK * TOPK + (size_t)row * 4) =
            make_float4(wn, wn, wn, wn);
    }
}

// capacity check from hist; out already holds the fast path. Single block:
// if any expert over capacity, run the exact serial fallback.
__global__ __launch_bounds__(256)
void k_decide(const int* __restrict__ hist, const float* __restrict__ logits,
              const float* __restrict__ maxv, const float* __restrict__ denomv,
              const int* __restrict__ tc, float* __restrict__ out,
              float* __restrict__ wtmp) {
    __shared__ int flagS;
    const int tid = threadIdx.x;
    const int cap = tc[0] / TOPK;
    if (tid < NE) {
        const bool bad = (TOPK * hist[tid * HSTR] > cap);
        const unsigned long long mm = __ballot(bad);
        if (tid == 0) flagS = (mm == 0ull) ? 1 : 0;
    }
    __syncthreads();
    if (flagS) return;                 // fast path already written

    if (tid < 64) {
        const int e = tid;
        int rem = cap;
        for (int k = 0; k < TOPK; ++k) {
            for (int b = 0; b < N_TOK; ++b) {
                const float lg = logits[(size_t)b * NE + e];
                float v = (rem > 0) ? lg : -INFINITY;
                int idx = e;
                #pragma unroll
                for (int off = 32; off; off >>= 1) {
                    const float ov = __shfl_xor(v, off);
                    const int   oi = __shfl_xor(idx, off);
                    if (ov > v || (ov == v && oi < idx)) { v = ov; idx = oi; }
                }
                const bool ok = (v != -INFINITY);
                if (ok && e == idx) rem -= 1;
                const float lc = __shfl(lg, idx);
                if (e == 0) {
                    out[(size_t)b * TOPK + k]  = ok ? (float)idx : -1.0f;
                    wtmp[(size_t)b * TOPK + k] = ok ? expf(lc - maxv[b]) / denomv[b] : 0.0f;
                }
            }
        }
    }
    __syncthreads();
    for (int b = tid; b < N_TOK; b += 256) {
        const float w0 = wtmp[b * 4 + 0], w1_ = wtmp[b * 4 + 1];
        const float w2 = wtmp[b * 4 + 2], w3 = wtmp[b * 4 + 3];
        const float s = ((w0 + w1_) + w2) + w3 + 1e-8f;
        out[N_TOK * TOPK + b * 4 + 0] = w0 / s;
        out[N_TOK * TOPK + b * 4 + 1] = w1_ / s;
        out[N_TOK * TOPK + b * 4 + 2] = w2 / s;
        out[N_TOK * TOPK + b * 4 + 3] = w3 / s;
    }
}

extern "C" void kernel_launch(void* const* d_in, const int* in_sizes, int n_in,
                              void* d_out, int out_size, void* d_ws, size_t ws_size,
                              hipStream_t stream) {
    const float* x    = (const float*)d_in[0];
    const float* W    = (const float*)d_in[1];
    const float* bias = (const float*)d_in[2];
    const int*   tc   = (const int*)d_in[3];

    float* ws       = (float*)d_ws;
    float* logits   = ws + OFF_LOGITS;
    float* Pp       = ws + OFF_P;
    float* maxv     = ws + OFF_MAXV;
    float* denomv   = ws + OFF_DENOM;
    int*   hist     = (int*)(ws + OFF_HIST);
    unsigned short* wh2 = (unsigned short*)(ws + OFF_WH);
    unsigned short* wl2 = (unsigned short*)(ws + OFF_WL);
    float* wt       = ws + OFF_WT;
    float* wtmp     = ws + OFF_WTMP;
    float* out      = (float*)d_out;

    k_wc<<<NE * DIM / 8 / 256, 256, 0, stream>>>(W, wh2, wl2, wt, hist);
    k_main<<<NBLK2, 512, 0, stream>>>(x, wh2, wl2, Pp);
    k_reduce<<<N_TOK / 32, 256, 0, stream>>>(Pp, bias, x, wt, logits, maxv,
                                             denomv, hist, out);
    k_decide<<<1, 256, 0, stream>>>(hist, logits, maxv, denomv, tc, out, wtmp);
}

// Round 12
// 148.239 us; speedup vs baseline: 2.1751x; 1.0328x over previous
//
#include <hip/hip_runtime.h>
#include <math.h>

#define N_TOK 8192
#define DIM   2048
#define NE    64
#define TOPK  4
#define THETA 2e-4f
#define TPB   64                      /* tokens per strip */
#define NSPL  4                       /* K splits */
#define NSTRIP (N_TOK / TPB)          /* 128 */
#define NBLK2 (NSTRIP * NSPL)         /* 512 blocks */
#define HSTR  16                      /* hist padding: 1 counter per 64B line */

typedef short bf16x8 __attribute__((ext_vector_type(8)));
typedef float f32x4  __attribute__((ext_vector_type(4)));

// ---- workspace layout (float offsets) ----
#define OFF_LOGITS 0                          /* final logits, N_TOK*NE */
#define OFF_P      (OFF_LOGITS + N_TOK * NE)  /* partials, NSPL*N_TOK*NE */
#define OFF_MAXV   (OFF_P + NSPL * N_TOK * NE)
#define OFF_DENOM  (OFF_MAXV + N_TOK)
#define OFF_HIST   (OFF_DENOM + N_TOK)        /* int, NE*HSTR = 1024 */
#define OFF_WH     (OFF_HIST + NE * HSTR)     /* NE*DIM bf16, frag-packed */
#define OFF_WL     (OFF_WH + NE * DIM / 2)
#define OFF_WT     (OFF_WL + NE * DIM / 2)    /* NE*DIM fp32 transposed */
#define OFF_WTMP   (OFF_WT + NE * DIM)        /* N_TOK*TOPK */

// pack 2 fp32 -> 2 truncated bf16 (hi) and 2 truncated bf16 of residual (lo)
__device__ inline void cvt2(float a, float b, unsigned& hi, unsigned& lo) {
    const unsigned ua = __float_as_uint(a), ub = __float_as_uint(b);
    hi = __builtin_amdgcn_perm(ub, ua, 0x07060302u);   // [a_hi16, b_hi16]
    const float ra = a - __uint_as_float(ua & 0xFFFF0000u);
    const float rb = b - __uint_as_float(ub & 0xFFFF0000u);
    lo = __builtin_amdgcn_perm(__float_as_uint(rb), __float_as_uint(ra), 0x07060302u);
}

union FragU { unsigned u[4]; bf16x8 v; uint4 q; };

__device__ inline void make_frags(const float4& p, const float4& q,
                                  bf16x8& hi, bf16x8& lo) {
    FragU H, L;
    cvt2(p.x, p.y, H.u[0], L.u[0]);
    cvt2(p.z, p.w, H.u[1], L.u[1]);
    cvt2(q.x, q.y, H.u[2], L.u[2]);
    cvt2(q.z, q.w, H.u[3], L.u[3]);
    hi = H.v; lo = L.v;
}

// W -> frag-packed (wh2, wl2): element for (kc, nt, lane, j) is
// W[e = nt*16 + (lane&15)][k = kc*32 + (lane>>4)*8 + j] at elem offset
// (kc*4+nt)*512 + lane*8 + j.  kc-major => the B slice of a 128-k window
// wk is the contiguous 16KB at wk*16384 bytes.  Also wt fp32 transpose
// [k][e] for the exact recompute; zero hist.
__global__ __launch_bounds__(256)
void k_wc(const float* __restrict__ W, unsigned short* __restrict__ wh2,
          unsigned short* __restrict__ wl2, float* __restrict__ wt,
          int* __restrict__ hist) {
    const int t = blockIdx.x * 256 + threadIdx.x;     // 0..16383
    if (t < NE * HSTR) hist[t] = 0;
    const int l  = t & 63;
    const int grp = t >> 6;                           // = kc*4 + nt, 0..255
    const int nt = grp & 3;
    const int kc = grp >> 2;
    const int e  = nt * 16 + (l & 15);
    const int k0 = kc * 32 + (l >> 4) * 8;

    const float4 p = *reinterpret_cast<const float4*>(W + (size_t)e * DIM + k0);
    const float4 q = *reinterpret_cast<const float4*>(W + (size_t)e * DIM + k0 + 4);
    FragU H, L;
    cvt2(p.x, p.y, H.u[0], L.u[0]);
    cvt2(p.z, p.w, H.u[1], L.u[1]);
    cvt2(q.x, q.y, H.u[2], L.u[2]);
    cvt2(q.z, q.w, H.u[3], L.u[3]);
    const size_t off = (size_t)grp * 512 + l * 8;
    *reinterpret_cast<uint4*>(wh2 + off) = H.q;
    *reinterpret_cast<uint4*>(wl2 + off) = L.q;

    wt[(size_t)(k0 + 0) * NE + e] = p.x;
    wt[(size_t)(k0 + 1) * NE + e] = p.y;
    wt[(size_t)(k0 + 2) * NE + e] = p.z;
    wt[(size_t)(k0 + 3) * NE + e] = p.w;
    wt[(size_t)(k0 + 4) * NE + e] = q.x;
    wt[(size_t)(k0 + 5) * NE + e] = q.y;
    wt[(size_t)(k0 + 6) * NE + e] = q.z;
    wt[(size_t)(k0 + 7) * NE + e] = q.w;
}

// Split-K GEMM: block (strip, kq) computes 64 tokens x 64 experts over
// k in [kq*512, +512).  512 blocks -> 2/CU.  4 windows of K=128, each
// staged 64KB via global_load_lds.  8 waves = 4 token-groups x 2
// expert-groups(32).  Full 4-product split-bf16 (ah*bh + al*bh + ah*bl
// + al*bl): logit error is pure fp32 accumulation-order noise (~2e-6).
// Raw partials to P[kq]; NO cross-block sync (kernel boundary = fence).
__global__ __launch_bounds__(512, 4)
void k_main(const float* __restrict__ x, const unsigned short* __restrict__ wh2,
            const unsigned short* __restrict__ wl2, float* __restrict__ P) {
    __shared__ __align__(16) char smem[65536];   // A 32K | Bh 16K | Bl 16K

    const int tid   = threadIdx.x;
    const int ww    = tid >> 6;          // wave 0..7
    const int l     = tid & 63;
    const int strip = blockIdx.x >> 2;
    const int kq    = blockIdx.x & 3;
    const int t0    = strip * TPB;
    const int m     = l & 15;            // token-low (A) / expert-low (B)
    const int g     = l >> 4;            // k-octet group
    const int tg    = ww >> 1;           // token group 0..3
    const int eg    = ww & 1;            // expert group 0..1 (32 experts)

    f32x4 accA[2], accB[2];
    #pragma unroll
    for (int n = 0; n < 2; ++n)
        #pragma unroll
        for (int r = 0; r < 4; ++r) { accA[n][r] = 0.0f; accB[n][r] = 0.0f; }

    const int arow = tg * 16 + m;        // A row this lane feeds (0..63)
    const int axor = arow & 15;          // A slot swizzle

    for (int win = 0; win < 4; ++win) {
        const int wk = kq * 4 + win;     // global 128-k window index
        // ---- stage 64KB: wave ww copies bytes [ww*8192, +8192) ----
        #pragma unroll
        for (int j = 0; j < 8; ++j) {
            const int dbase = ww * 8192 + j * 1024;    // wave-uniform
            const int d = dbase + l * 16;
            const char* src;
            if (dbase < 32768) {
                const int r = d >> 9;                  // token row 0..63
                const int p = (d >> 4) & 31;           // physical 16B slot
                const int s = p ^ (r & 15);            // logical slot
                src = (const char*)(x + (size_t)(t0 + r) * DIM
                                    + wk * 128 + s * 4);
            } else if (dbase < 49152) {
                src = (const char*)wh2 + (size_t)wk * 16384 + (d - 32768);
            } else {
                src = (const char*)wl2 + (size_t)wk * 16384 + (d - 49152);
            }
            __builtin_amdgcn_global_load_lds(
                (const __attribute__((address_space(1))) void*)src,
                (__attribute__((address_space(3))) void*)(smem + dbase),
                16, 0, 0);
        }
        asm volatile("s_waitcnt vmcnt(0)" ::: "memory");
        __syncthreads();

        // ---- compute: 4 k-chunks x {A reads+cvt, 2 nt-tiles x 4 MFMA} ----
        const char* A = smem + arow * 512;
        #pragma unroll
        for (int kc = 0; kc < 4; ++kc) {
            const int s0 = kc * 8 + g * 2;
            const float4 pf = *reinterpret_cast<const float4*>(A + ((s0 ^ axor) << 4));
            const float4 qf = *reinterpret_cast<const float4*>(A + (((s0 + 1) ^ axor) << 4));
            bf16x8 ah, al;
            make_frags(pf, qf, ah, al);
            #pragma unroll
            for (int n = 0; n < 2; ++n) {
                const int nt = eg * 2 + n;
                FragU bh_, bl_;
                bh_.q = *reinterpret_cast<const uint4*>(smem + 32768 + (kc * 4 + nt) * 1024 + l * 16);
                bl_.q = *reinterpret_cast<const uint4*>(smem + 49152 + (kc * 4 + nt) * 1024 + l * 16);
                accA[n] = __builtin_amdgcn_mfma_f32_16x16x32_bf16(ah, bh_.v, accA[n], 0, 0, 0);
                accB[n] = __builtin_amdgcn_mfma_f32_16x16x32_bf16(al, bh_.v, accB[n], 0, 0, 0);
                accB[n] = __builtin_amdgcn_mfma_f32_16x16x32_bf16(ah, bl_.v, accB[n], 0, 0, 0);
                accB[n] = __builtin_amdgcn_mfma_f32_16x16x32_bf16(al, bl_.v, accB[n], 0, 0, 0);
            }
        }
        __syncthreads();
    }

    // ---- raw partial store (C/D map: col=lane&15=expert-low, row=g*4+r) ----
    float* dst = P + (size_t)kq * N_TOK * NE;
    #pragma unroll
    for (int n = 0; n < 2; ++n)
        #pragma unroll
        for (int r = 0; r < 4; ++r)
            dst[(size_t)(t0 + tg * 16 + g * 4 + r) * NE + eg * 32 + n * 16 + m] =
                accA[n][r] + accB[n][r];
}

// Reduce partials + bias -> logits; stats; THETA-flagged exact recompute
// (LDS-staged x + coalesced float4 wt reads); histogram; fast-path out.
// 256 blocks x 256 thr, 32 tokens each.
__global__ __launch_bounds__(256)
void k_reduce(const float* __restrict__ P, const float* __restrict__ bias,
              const float* __restrict__ x, const float* __restrict__ wt,
              float* __restrict__ logits, float* __restrict__ maxv,
              float* __restrict__ denomv, int* __restrict__ hist,
              float* __restrict__ out) {
    __shared__ float lbuf[32][68];
    __shared__ float part[4][68];
    __shared__ float xs[DIM];            // 8 KB, staged x row for recompute
    __shared__ int   selS[32];
    __shared__ float wS[32];
    __shared__ short flagIdx[32];
    __shared__ int   flagCnt;

    const int tid = threadIdx.x;
    const int ww  = tid >> 6;            // wave 0..3
    const int l   = tid & 63;
    const int t0  = blockIdx.x * 32;

    if (tid == 0) flagCnt = 0;

    // sum 4 partials + bias (float4 over experts)
    for (int q = tid; q < 32 * 16; q += 256) {
        const int t = q >> 4, e4 = (q & 15) << 2;
        const size_t idx = (size_t)(t0 + t) * NE + e4;
        float4 s = *reinterpret_cast<const float4*>(P + idx);
        const float4 b1 = *reinterpret_cast<const float4*>(P + (size_t)N_TOK * NE + idx);
        const float4 b2 = *reinterpret_cast<const float4*>(P + (size_t)2 * N_TOK * NE + idx);
        const float4 b3 = *reinterpret_cast<const float4*>(P + (size_t)3 * N_TOK * NE + idx);
        const float4 bb = *reinterpret_cast<const float4*>(bias + e4);
        s.x += b1.x + b2.x + b3.x + bb.x;
        s.y += b1.y + b2.y + b3.y + bb.y;
        s.z += b1.z + b2.z + b3.z + bb.z;
        s.w += b1.w + b2.w + b3.w + bb.w;
        *reinterpret_cast<float4*>(logits + idx) = s;
        *reinterpret_cast<float4*>(&lbuf[t][e4]) = s;
    }
    __syncthreads();

    #pragma unroll
    for (int tt = 0; tt < 8; ++tt) {
        const int t = ww * 8 + tt;
        const float lv = lbuf[t][l];
        float v1 = lv; int i1 = l; float v2 = -INFINITY;
        #pragma unroll
        for (int off = 32; off; off >>= 1) {
            const float ov1 = __shfl_xor(v1, off);
            const int   oi1 = __shfl_xor(i1, off);
            const float ov2 = __shfl_xor(v2, off);
            if (ov1 > v1 || (ov1 == v1 && oi1 < i1)) {
                v2 = fmaxf(v1, ov2); v1 = ov1; i1 = oi1;
            } else {
                v2 = fmaxf(v2, ov1);
            }
        }
        float s = expf(lv - v1);
        #pragma unroll
        for (int off = 32; off; off >>= 1) s += __shfl_xor(s, off);
        if (l == 0) {
            const int row = t0 + t;
            maxv[row]   = v1;
            denomv[row] = s;
            selS[t]     = i1;
            wS[t]       = 1.0f / s;
            if (v1 - v2 < THETA) {
                const int ix = atomicAdd(&flagCnt, 1);
                flagIdx[ix] = (short)t;
            }
        }
    }
    __syncthreads();

    // ---- exact fp32 recompute for flagged (near-tie) tokens ----
    // x row staged in LDS; wt read as coalesced float4 expert-quads
    // (wave instr = 1KB contiguous, 4 k's retired per instr, deep ILP).
    const int nf = flagCnt;
    for (int fi = 0; fi < nf; ++fi) {
        const int tl  = flagIdx[fi];
        const int row = t0 + tl;
        for (int j = tid; j < DIM / 4; j += 256)
            *reinterpret_cast<float4*>(&xs[j * 4]) =
                *reinterpret_cast<const float4*>(x + (size_t)row * DIM + j * 4);
        __syncthreads();

        const int eq = l & 15;           // expert-quad index (float4 #)
        const int kg = l >> 4;           // k subgroup 0..3
        const float4* wt4 = reinterpret_cast<const float4*>(wt);  // [k][16]
        float4 acc = make_float4(0.f, 0.f, 0.f, 0.f);
        #pragma unroll 8
        for (int i = 0; i < 128; ++i) {
            const int k = ww * 512 + i * 4 + kg;
            const float4 wq = wt4[(size_t)k * 16 + eq];
            const float xv = xs[k];
            acc.x = fmaf(xv, wq.x, acc.x);
            acc.y = fmaf(xv, wq.y, acc.y);
            acc.z = fmaf(xv, wq.z, acc.z);
            acc.w = fmaf(xv, wq.w, acc.w);
        }
        // reduce across the 4 k-subgroups (lanes ^16, ^32)
        #pragma unroll
        for (int off = 16; off <= 32; off <<= 1) {
            acc.x += __shfl_xor(acc.x, off);
            acc.y += __shfl_xor(acc.y, off);
            acc.z += __shfl_xor(acc.z, off);
            acc.w += __shfl_xor(acc.w, off);
        }
        if (l < 16) *reinterpret_cast<float4*>(&part[ww][l * 4]) = acc;
        __syncthreads();
        if (ww == 0) {
            float lg = bias[l];
            #pragma unroll
            for (int s2 = 0; s2 < 4; ++s2) lg += part[s2][l];
            logits[(size_t)row * NE + l] = lg;
            float v = lg; int idx = l;
            #pragma unroll
            for (int off = 32; off; off >>= 1) {
                const float ov = __shfl_xor(v, off);
                const int   oi = __shfl_xor(idx, off);
                if (ov > v || (ov == v && oi < idx)) { v = ov; idx = oi; }
            }
            float p = expf(lg - v);
            #pragma unroll
            for (int off = 32; off; off >>= 1) p += __shfl_xor(p, off);
            if (l == 0) {
                maxv[row]   = v;
                denomv[row] = p;
                selS[tl]    = idx;
                wS[tl]      = 1.0f / p;
            }
        }
        __syncthreads();
    }

    // ---- selection histogram: wave 0, lane = expert; padded counters ----
    if (ww == 0) {
        int cnt = 0;
        #pragma unroll
        for (int t = 0; t < 32; ++t) cnt += (selS[t] == l) ? 1 : 0;
        if (cnt) atomicAdd(&hist[l * HSTR], cnt);
    }

    // ---- fast-path out write (k_decide fixes up only on capacity overflow) --
    if (tid < 32) {
        const int row = t0 + tid;
        const float se = (float)selS[tid];
        const float wv = wS[tid];
        const float wn = wv / (4.0f * wv + 1e-8f);
        *reinterpret_cast<float4*>(out + (size_t)row * 4) = make_float4(se, se, se, se);
        *reinterpret_cast<float4*>(out + (size_t)N_TOK * TOPK + (size_t)row * 4) =
            make_float4(wn, wn, wn, wn);
    }
}

// capacity check from hist; out already holds the fast path. Single block:
// if any expert over capacity, run the exact serial fallback.
__global__ __launch_bounds__(256)
void k_decide(const int* __restrict__ hist, const float* __restrict__ logits,
              const float* __restrict__ maxv, const float* __restrict__ denomv,
              const int* __restrict__ tc, float* __restrict__ out,
              float* __restrict__ wtmp) {
    __shared__ int flagS;
    const int tid = threadIdx.x;
    const int cap = tc[0] / TOPK;
    if (tid < NE) {
        const bool bad = (TOPK * hist[tid * HSTR] > cap);
        const unsigned long long mm = __ballot(bad);
        if (tid == 0) flagS = (mm == 0ull) ? 1 : 0;
    }
    __syncthreads();
    if (flagS) return;                 // fast path already written

    if (tid < 64) {
        const int e = tid;
        int rem = cap;
        for (int k = 0; k < TOPK; ++k) {
            for (int b = 0; b < N_TOK; ++b) {
                const float lg = logits[(size_t)b * NE + e];
                float v = (rem > 0) ? lg : -INFINITY;
                int idx = e;
                #pragma unroll
                for (int off = 32; off; off >>= 1) {
                    const float ov = __shfl_xor(v, off);
                    const int   oi = __shfl_xor(idx, off);
                    if (ov > v || (ov == v && oi < idx)) { v = ov; idx = oi; }
                }
                const bool ok = (v != -INFINITY);
                if (ok && e == idx) rem -= 1;
                const float lc = __shfl(lg, idx);
                if (e == 0) {
                    out[(size_t)b * TOPK + k]  = ok ? (float)idx : -1.0f;
                    wtmp[(size_t)b * TOPK + k] = ok ? expf(lc - maxv[b]) / denomv[b] : 0.0f;
                }
            }
        }
    }
    __syncthreads();
    for (int b = tid; b < N_TOK; b += 256) {
        const float w0 = wtmp[b * 4 + 0], w1_ = wtmp[b * 4 + 1];
        const float w2 = wtmp[b * 4 + 2], w3 = wtmp[b * 4 + 3];
        const float s = ((w0 + w1_) + w2) + w3 + 1e-8f;
        out[N_TOK * TOPK + b * 4 + 0] = w0 / s;
        out[N_TOK * TOPK + b * 4 + 1] = w1_ / s;
        out[N_TOK * TOPK + b * 4 + 2] = w2 / s;
        out[N_TOK * TOPK + b * 4 + 3] = w3 / s;
    }
}

extern "C" void kernel_launch(void* const* d_in, const int* in_sizes, int n_in,
                              void* d_out, int out_size, void* d_ws, size_t ws_size,
                              hipStream_t stream) {
    const float* x    = (const float*)d_in[0];
    const float* W    = (const float*)d_in[1];
    const float* bias = (const float*)d_in[2];
    const int*   tc   = (const int*)d_in[3];

    float* ws       = (float*)d_ws;
    float* logits   = ws + OFF_LOGITS;
    float* Pp       = ws + OFF_P;
    float* maxv     = ws + OFF_MAXV;
    float* denomv   = ws + OFF_DENOM;
    int*   hist     = (int*)(ws + OFF_HIST);
    unsigned short* wh2 = (unsigned short*)(ws + OFF_WH);
    unsigned short* wl2 = (unsigned short*)(ws + OFF_WL);
    float* wt       = ws + OFF_WT;
    float* wtmp     = ws + OFF_WTMP;
    float* out      = (float*)d_out;

    k_wc<<<NE * DIM / 8 / 256, 256, 0, stream>>>(W, wh2, wl2, wt, hist);
    k_main<<<NBLK2, 512, 0, stream>>>(x, wh2, wl2, Pp);
    k_reduce<<<N_TOK / 32, 256, 0, stream>>>(Pp, bias, x, wt, logits, maxv,
                                             denomv, hist, out);
    k_decide<<<1, 256, 0, stream>>>(hist, logits, maxv, denomv, tc, out, wtmp);
}